// Round 1
// baseline (111.074 us; speedup 1.0000x reference)
//
#include <hip/hip_runtime.h>
#include <math.h>

#define BATCH 2
#define HH 384
#define WW 384
#define HWSZ (HH * WW)
#define NPIX (BATCH * HWSZ)
#define KR 5      // kernel radius (K=11)
#define KSEL 11   // top-k count
#define NBLK (NPIX / 256)   // 1152, exact

__device__ __forceinline__ float wave_sum(float v) {
#pragma unroll
    for (int off = 32; off > 0; off >>= 1) v += __shfl_down(v, off, 64);
    return v;
}

__global__ __launch_bounds__(256) void matting_main(
    const float* __restrict__ alpha,
    const float* __restrict__ trimap,
    const float* __restrict__ image,
    float* __restrict__ ws)   // ws[block*4 + {0..3}] partials
{
    const int pix = blockIdx.x * 256 + threadIdx.x;   // grid sized exactly
    const int b = pix / HWSZ;
    const int rem = pix - b * HWSZ;
    const int y = rem / WW;
    const int x = rem - y * WW;

    const float* i0 = image + b * 3 * HWSZ;
    const float* i1 = i0 + HWSZ;
    const float* i2 = i1 + HWSZ;
    const float* ap = alpha + b * HWSZ;

    // de-normalize center pixel: img = image*std + mean
    const float c0 = i0[rem] * 0.229f + 0.485f;
    const float c1 = i1[rem] * 0.224f + 0.456f;
    const float c2 = i2[rem] * 0.225f + 0.406f;
    const float ac = ap[rem];
    const float tri = trimap[b * HWSZ + rem];

    // top-11 smallest distances (ascending) + paired alpha-diffs, in registers
    float bd[KSEL], ba[KSEL];
#pragma unroll
    for (int j = 0; j < KSEL; ++j) { bd[j] = 3.4e38f; ba[j] = 0.f; }

    const float pad_d = sqrtf(c0 * c0 + c1 * c1 + c2 * c2);  // dist to zero-pad

    for (int di = -KR; di <= KR; ++di) {
        const int yy = y + di;
        const bool rowok = (yy >= 0) && (yy < HH);
        const int rowbase = yy * WW;
        for (int dj = -KR; dj <= KR; ++dj) {
            const int xx = x + dj;
            float d, adiff;
            if (rowok && xx >= 0 && xx < WW) {
                const int ni = rowbase + xx;
                const float n0 = i0[ni] * 0.229f + 0.485f;
                const float n1 = i1[ni] * 0.224f + 0.456f;
                const float n2 = i2[ni] * 0.225f + 0.406f;
                const float e0 = c0 - n0, e1 = c1 - n1, e2 = c2 - n2;
                d = sqrtf(e0 * e0 + e1 * e1 + e2 * e2);
                adiff = ac - ap[ni];
            } else {
                d = pad_d;       // neighbor is the zero vector
                adiff = ac;      // alpha - 0
            }
            // insert into sorted top-11 (stable: ties keep earlier index, matches top_k)
            if (d < bd[KSEL - 1]) {
                float cd = d, ca = adiff;
#pragma unroll
                for (int j = 0; j < KSEL; ++j) {
                    const bool sw = cd < bd[j];
                    const float td = bd[j], ta = ba[j];
                    bd[j] = sw ? cd : td;
                    ba[j] = sw ? ca : ta;
                    cd = sw ? td : cd;
                    ca = sw ? ta : ca;
                }
            }
        }
    }

    // known-region L1:  mask = (tri != 0.5); |pred*m - tri*m| = m*|pred-tri|
    const float known_c = (tri != 0.5f) ? 1.f : 0.f;
    const float known_v = known_c * fabsf(ac - tri);
    // ddc: sample_map = (tri == 0.5); sum |d_i - a_i| over selected set
    const float samp = (tri == 0.5f) ? 1.f : 0.f;
    float dsum = 0.f;
#pragma unroll
    for (int j = 0; j < KSEL; ++j) dsum += fabsf(bd[j] - ba[j]);
    dsum *= samp;

    // deterministic block reduction (4 waves of 64)
    float v0 = wave_sum(known_v);
    float v1 = wave_sum(known_c);
    float v2 = wave_sum(dsum);
    float v3 = wave_sum(samp);
    __shared__ float sred[4][4];
    const int wid = threadIdx.x >> 6, lane = threadIdx.x & 63;
    if (lane == 0) { sred[wid][0] = v0; sred[wid][1] = v1; sred[wid][2] = v2; sred[wid][3] = v3; }
    __syncthreads();
    if (threadIdx.x == 0) {
        float a = 0, bb = 0, c = 0, dd = 0;
#pragma unroll
        for (int w = 0; w < 4; ++w) { a += sred[w][0]; bb += sred[w][1]; c += sred[w][2]; dd += sred[w][3]; }
        float* wsb = ws + blockIdx.x * 4;
        wsb[0] = a; wsb[1] = bb; wsb[2] = c; wsb[3] = dd;
    }
}

__global__ __launch_bounds__(256) void matting_finalize(
    const float* __restrict__ ws, float* __restrict__ out)
{
    float a = 0, b = 0, c = 0, d = 0;
    for (int i = threadIdx.x; i < NBLK; i += 256) {
        a += ws[i * 4 + 0];
        b += ws[i * 4 + 1];
        c += ws[i * 4 + 2];
        d += ws[i * 4 + 3];
    }
    a = wave_sum(a); b = wave_sum(b); c = wave_sum(c); d = wave_sum(d);
    __shared__ float sred[4][4];
    const int wid = threadIdx.x >> 6, lane = threadIdx.x & 63;
    if (lane == 0) { sred[wid][0] = a; sred[wid][1] = b; sred[wid][2] = c; sred[wid][3] = d; }
    __syncthreads();
    if (threadIdx.x == 0) {
        float ksum = 0, kcnt = 0, dsum = 0, scnt = 0;
#pragma unroll
        for (int w = 0; w < 4; ++w) {
            ksum += sred[w][0]; kcnt += sred[w][1]; dsum += sred[w][2]; scnt += sred[w][3];
        }
        const float known = (kcnt > 0.f) ? ksum * (1.0f / (float)NPIX) : 0.f;
        const float ddc   = (scnt > 0.f) ? dsum * (0.1f / ((float)NPIX * (float)KSEL)) : 0.f;
        out[0] = known + ddc;   // total
        out[1] = known;         // known_l1
        out[2] = ddc;           // ddc
    }
}

extern "C" void kernel_launch(void* const* d_in, const int* in_sizes, int n_in,
                              void* d_out, int out_size, void* d_ws, size_t ws_size,
                              hipStream_t stream) {
    const float* alpha  = (const float*)d_in[0];  // pred_alpha  [2,1,384,384]
    const float* trimap = (const float*)d_in[1];  // gt_trimap   [2,1,384,384]
    const float* image  = (const float*)d_in[2];  // input_image [2,3,384,384]
    float* out = (float*)d_out;                   // 3 floats: total, known_l1, ddc
    float* ws  = (float*)d_ws;                    // NBLK*4 floats of partials

    matting_main<<<NBLK, 256, 0, stream>>>(alpha, trimap, image, ws);
    matting_finalize<<<1, 256, 0, stream>>>(ws, out);
}

// Round 2
// 48.816 us; speedup vs baseline: 2.2754x; 2.2754x over previous
//
#include <hip/hip_runtime.h>
#include <math.h>

#define HH 384
#define WW 384
#define HWSZ (HH * WW)
#define NPIX (2 * HWSZ)
#define KSEL 11
#define TB 16            // output tile edge
#define TP (TB + 10)     // padded tile edge = 26
#define NBLK (NPIX / 256) // 1152 blocks of 256 threads (16x16 tile each)

__device__ __forceinline__ float fast_sqrtf(float x) {
    float r;
    asm("v_sqrt_f32 %0, %1" : "=v"(r) : "v"(x));
    return r;
}

__device__ __forceinline__ float wave_sum(float v) {
#pragma unroll
    for (int off = 32; off > 0; off >>= 1) v += __shfl_down(v, off, 64);
    return v;
}

// d^2 between denormalized center c and neighbor n.
// MUST be bit-identical between pass 1 and pass 2: fixed op order via fmaf.
__device__ __forceinline__ float dist2(const float4 c, const float4 n) {
    const float e0 = c.x - n.x;
    const float e1 = c.y - n.y;
    const float e2 = c.z - n.z;
    float d2 = e0 * e0;
    d2 = __builtin_fmaf(e1, e1, d2);
    d2 = __builtin_fmaf(e2, e2, d2);
    return d2;
}

__global__ __launch_bounds__(256) void matting_main(
    const float* __restrict__ alpha,
    const float* __restrict__ trimap,
    const float* __restrict__ image,
    float* __restrict__ ws)
{
    __shared__ float4 tile[TP * TP];   // denormalized rgb + alpha, zero-padded

    const int bx = blockIdx.x % 24;
    const int by = (blockIdx.x / 24) % 24;
    const int b  = blockIdx.x / 576;

    const float* i0 = image + b * 3 * HWSZ;
    const float* i1 = i0 + HWSZ;
    const float* i2 = i1 + HWSZ;
    const float* ap = alpha + b * HWSZ;

    // ---- stage padded, denormalized tile into LDS (pad = zeros, exactly as
    // the reference's zero-padded unfold of the denormalized image) ----
    const int gy0 = by * TB - 5, gx0 = bx * TB - 5;
    for (int t = threadIdx.x; t < TP * TP; t += 256) {
        const int ry = t / TP, rx = t - ry * TP;
        const int gy = gy0 + ry, gx = gx0 + rx;
        float4 v = make_float4(0.f, 0.f, 0.f, 0.f);
        if ((unsigned)gy < (unsigned)HH && (unsigned)gx < (unsigned)WW) {
            const int gi = gy * WW + gx;
            v.x = __builtin_fmaf(i0[gi], 0.229f, 0.485f);
            v.y = __builtin_fmaf(i1[gi], 0.224f, 0.456f);
            v.z = __builtin_fmaf(i2[gi], 0.225f, 0.406f);
            v.w = ap[gi];
        }
        tile[t] = v;
    }
    __syncthreads();

    const int tx = threadIdx.x & 15, ty = threadIdx.x >> 4;
    const float4 c = tile[(ty + 5) * TP + (tx + 5)];
    const float ac = c.w;

    // ---- pass 1: top-11 smallest d^2, payload-free branchless min/max bubble ----
    float bd[KSEL];
#pragma unroll
    for (int j = 0; j < KSEL; ++j) bd[j] = 3.4e38f;

    for (int di = 0; di < 11; ++di) {
        const float4* row = &tile[(ty + di) * TP + tx];
#pragma unroll
        for (int dj = 0; dj < 11; ++dj) {
            float cd = dist2(c, row[dj]);
#pragma unroll
            for (int j = 0; j < KSEL; ++j) {
                const float mx = fmaxf(cd, bd[j]);
                bd[j] = fminf(cd, bd[j]);
                cd = mx;
            }
        }
    }

    const float thr = bd[KSEL - 1];          // 11th smallest d^2
    int need = KSEL;                          // how many ==thr entries to take
#pragma unroll
    for (int j = 0; j < KSEL - 1; ++j) need -= (bd[j] < thr) ? 1 : 0;

    // ---- pass 2: recompute d^2 (bit-identical), accumulate over selected set.
    // d2 < thr always taken; d2 == thr taken in index order while need > 0 —
    // exactly top_k's lower-index tie-break. ----
    float dsum = 0.f;
    for (int di = 0; di < 11; ++di) {
        const float4* row = &tile[(ty + di) * TP + tx];
#pragma unroll
        for (int dj = 0; dj < 11; ++dj) {
            const float4 n = row[dj];
            const float d2 = dist2(c, n);
            const bool lt = d2 < thr;
            const bool eq = (d2 == thr) && (need > 0);
            need -= eq ? 1 : 0;
            const float contrib = fabsf(fast_sqrtf(d2) - (ac - n.w));
            dsum += (lt || eq) ? contrib : 0.f;
        }
    }

    // ---- known-region L1 + masks for own pixel ----
    const int rem = (by * TB + ty) * WW + (bx * TB + tx);
    const float tri = trimap[b * HWSZ + rem];
    const float known_c = (tri != 0.5f) ? 1.f : 0.f;
    const float known_v = known_c * fabsf(ac - tri);
    const float samp = (tri == 0.5f) ? 1.f : 0.f;
    dsum *= samp;

    // ---- deterministic block reduction ----
    float v0 = wave_sum(known_v);
    float v1 = wave_sum(known_c);
    float v2 = wave_sum(dsum);
    float v3 = wave_sum(samp);
    __shared__ float sred[4][4];
    const int wid = threadIdx.x >> 6, lane = threadIdx.x & 63;
    if (lane == 0) { sred[wid][0] = v0; sred[wid][1] = v1; sred[wid][2] = v2; sred[wid][3] = v3; }
    __syncthreads();
    if (threadIdx.x == 0) {
        float a = 0, bb = 0, cc = 0, dd = 0;
#pragma unroll
        for (int w = 0; w < 4; ++w) { a += sred[w][0]; bb += sred[w][1]; cc += sred[w][2]; dd += sred[w][3]; }
        float* wsb = ws + blockIdx.x * 4;
        wsb[0] = a; wsb[1] = bb; wsb[2] = cc; wsb[3] = dd;
    }
}

__global__ __launch_bounds__(256) void matting_finalize(
    const float* __restrict__ ws, float* __restrict__ out)
{
    float a = 0, b = 0, c = 0, d = 0;
    for (int i = threadIdx.x; i < NBLK; i += 256) {
        a += ws[i * 4 + 0];
        b += ws[i * 4 + 1];
        c += ws[i * 4 + 2];
        d += ws[i * 4 + 3];
    }
    a = wave_sum(a); b = wave_sum(b); c = wave_sum(c); d = wave_sum(d);
    __shared__ float sred[4][4];
    const int wid = threadIdx.x >> 6, lane = threadIdx.x & 63;
    if (lane == 0) { sred[wid][0] = a; sred[wid][1] = b; sred[wid][2] = c; sred[wid][3] = d; }
    __syncthreads();
    if (threadIdx.x == 0) {
        float ksum = 0, kcnt = 0, dsum = 0, scnt = 0;
#pragma unroll
        for (int w = 0; w < 4; ++w) {
            ksum += sred[w][0]; kcnt += sred[w][1]; dsum += sred[w][2]; scnt += sred[w][3];
        }
        const float known = (kcnt > 0.f) ? ksum * (1.0f / (float)NPIX) : 0.f;
        const float ddc   = (scnt > 0.f) ? dsum * (0.1f / ((float)NPIX * (float)KSEL)) : 0.f;
        out[0] = known + ddc;
        out[1] = known;
        out[2] = ddc;
    }
}

extern "C" void kernel_launch(void* const* d_in, const int* in_sizes, int n_in,
                              void* d_out, int out_size, void* d_ws, size_t ws_size,
                              hipStream_t stream) {
    const float* alpha  = (const float*)d_in[0];  // pred_alpha  [2,1,384,384]
    const float* trimap = (const float*)d_in[1];  // gt_trimap   [2,1,384,384]
    const float* image  = (const float*)d_in[2];  // input_image [2,3,384,384]
    float* out = (float*)d_out;
    float* ws  = (float*)d_ws;

    matting_main<<<NBLK, 256, 0, stream>>>(alpha, trimap, image, ws);
    matting_finalize<<<1, 256, 0, stream>>>(ws, out);
}

// Round 3
// 43.437 us; speedup vs baseline: 2.5571x; 1.1238x over previous
//
#include <hip/hip_runtime.h>
#include <math.h>

#define HH 384
#define WW 384
#define HWSZ (HH * WW)
#define NPIX (2 * HWSZ)
#define KSEL 11
#define TW 64            // tile width (one wave per row)
#define TH 2             // tile height (2 waves per block)
#define TPW (TW + 10)    // 74
#define TPH (TH + 10)    // 12
#define NBX (WW / TW)    // 6
#define NBY (HH / TH)    // 192
#define NBLK (2 * NBX * NBY)  // 2304 = 9 * 256 -> perfect CU balance

__device__ __forceinline__ float fast_sqrtf(float x) {
    float r;
    asm("v_sqrt_f32 %0, %1" : "=v"(r) : "v"(x));
    return r;
}

__device__ __forceinline__ float min3f(float a, float b, float c) {
    float r;
    asm("v_min3_f32 %0, %1, %2, %3" : "=v"(r) : "v"(a), "v"(b), "v"(c));
    return r;
}

__device__ __forceinline__ float wave_sum(float v) {
#pragma unroll
    for (int off = 32; off > 0; off >>= 1) v += __shfl_down(v, off, 64);
    return v;
}

// Composite key: high 20 bits = d^2 (f32 bits truncated), low 12 = quantized
// alpha_diff. d2 >= 0 so float min/max order == lexicographic (d2, payload).
__device__ __forceinline__ float make_key(const float4 c, const float4 n) {
    const float e0 = c.x - n.x;
    const float e1 = c.y - n.y;
    const float e2 = c.z - n.z;
    float d2 = e0 * e0;
    d2 = __builtin_fmaf(e1, e1, d2);
    d2 = __builtin_fmaf(e2, e2, d2);
    const float ad = c.w - n.w;                         // in (-1, 1)
    const unsigned u = (unsigned)__builtin_fmaf(ad, 2047.0f, 2048.5f); // [1,4095]
    const unsigned bits = (__float_as_uint(d2) & 0xFFFFF000u) | u;
    return __uint_as_float(bits);
}

// Merge an unsorted pair into sorted-ascending bd[0..10], keep smallest 11.
// (n,2) merge network: outputs independent -> good ILP.
__device__ __forceinline__ void merge2(float bd[KSEL], float a, float b) {
    const float p0 = fminf(a, b);
    const float p1 = fmaxf(a, b);
    float nb[KSEL];
    nb[0] = fminf(bd[0], p0);
    nb[1] = min3f(bd[1], fmaxf(bd[0], p0), p1);
#pragma unroll
    for (int j = 2; j < KSEL; ++j)
        nb[j] = min3f(bd[j], fmaxf(bd[j - 1], p0), fmaxf(bd[j - 2], p1));
#pragma unroll
    for (int j = 0; j < KSEL; ++j) bd[j] = nb[j];
}

// Insert one value (classic 2-op/stage carry bubble).
__device__ __forceinline__ void merge1(float bd[KSEL], float p) {
    float cd = p;
#pragma unroll
    for (int j = 0; j < KSEL; ++j) {
        const float mx = fmaxf(cd, bd[j]);
        bd[j] = fminf(cd, bd[j]);
        cd = mx;
    }
}

__global__ __launch_bounds__(128) void matting_main(
    const float* __restrict__ alpha,
    const float* __restrict__ trimap,
    const float* __restrict__ image,
    float* __restrict__ ws)
{
    __shared__ float4 tile[TPH * TPW];   // denormalized rgb + alpha, zero pad

    const int bx = blockIdx.x % NBX;
    const int by = (blockIdx.x / NBX) % NBY;
    const int b  = blockIdx.x / (NBX * NBY);

    const float* i0 = image + b * 3 * HWSZ;
    const float* i1 = i0 + HWSZ;
    const float* i2 = i1 + HWSZ;
    const float* ap = alpha + b * HWSZ;

    const int gy0 = by * TH - 5, gx0 = bx * TW - 5;
    for (int t = threadIdx.x; t < TPH * TPW; t += 128) {
        const int ry = t / TPW, rx = t - ry * TPW;
        const int gy = gy0 + ry, gx = gx0 + rx;
        float4 v = make_float4(0.f, 0.f, 0.f, 0.f);
        if ((unsigned)gy < (unsigned)HH && (unsigned)gx < (unsigned)WW) {
            const int gi = gy * WW + gx;
            v.x = __builtin_fmaf(i0[gi], 0.229f, 0.485f);
            v.y = __builtin_fmaf(i1[gi], 0.224f, 0.456f);
            v.z = __builtin_fmaf(i2[gi], 0.225f, 0.406f);
            v.w = ap[gi];
        }
        tile[t] = v;
    }
    __syncthreads();

    const int lane = threadIdx.x & 63;
    const int w    = threadIdx.x >> 6;          // wave id = tile row
    const float4* tp = &tile[w * TPW + lane];   // candidate (di,dj) at tp[di*TPW+dj]
    const float4 c = tp[5 * TPW + 5];
    const float ac = c.w;

    float bd[KSEL];
#pragma unroll
    for (int j = 0; j < KSEL; ++j) bd[j] = __uint_as_float(0x7F800000u); // +inf

    for (int di = 0; di < 11; ++di) {
        const float4* row = tp + di * TPW;
#pragma unroll
        for (int h = 0; h < 5; ++h) {
            const float k0 = make_key(c, row[2 * h]);
            const float k1 = make_key(c, row[2 * h + 1]);
            merge2(bd, k0, k1);
        }
        merge1(bd, make_key(c, row[10]));
    }

    // unpack the 11 selected (dist, alpha_diff) pairs and accumulate
    float dsum = 0.f;
#pragma unroll
    for (int j = 0; j < KSEL; ++j) {
        const unsigned kb = __float_as_uint(bd[j]);
        const float d2 = __uint_as_float((kb & 0xFFFFF000u) | 0x800u); // midpoint
        const float ad = __builtin_fmaf((float)(kb & 0xFFFu),
                                        1.0f / 2047.0f, -2048.0f / 2047.0f);
        dsum += fabsf(fast_sqrtf(d2) - ad);
    }

    // own-pixel masks / known L1
    const int rem = (by * TH + w) * WW + (bx * TW + lane);
    const float tri = trimap[b * HWSZ + rem];
    const float known_c = (tri != 0.5f) ? 1.f : 0.f;
    const float known_v = known_c * fabsf(ac - tri);
    const float samp = (tri == 0.5f) ? 1.f : 0.f;
    dsum *= samp;

    // deterministic block reduction (2 waves)
    float v0 = wave_sum(known_v);
    float v1 = wave_sum(known_c);
    float v2 = wave_sum(dsum);
    float v3 = wave_sum(samp);
    __shared__ float sred[2][4];
    if (lane == 0) { sred[w][0] = v0; sred[w][1] = v1; sred[w][2] = v2; sred[w][3] = v3; }
    __syncthreads();
    if (threadIdx.x == 0) {
        float* wsb = ws + blockIdx.x * 4;
        wsb[0] = sred[0][0] + sred[1][0];
        wsb[1] = sred[0][1] + sred[1][1];
        wsb[2] = sred[0][2] + sred[1][2];
        wsb[3] = sred[0][3] + sred[1][3];
    }
}

__global__ __launch_bounds__(256) void matting_finalize(
    const float* __restrict__ ws, float* __restrict__ out)
{
    float a = 0, b = 0, c = 0, d = 0;
    for (int i = threadIdx.x; i < NBLK; i += 256) {
        a += ws[i * 4 + 0];
        b += ws[i * 4 + 1];
        c += ws[i * 4 + 2];
        d += ws[i * 4 + 3];
    }
    a = wave_sum(a); b = wave_sum(b); c = wave_sum(c); d = wave_sum(d);
    __shared__ float sred[4][4];
    const int wid = threadIdx.x >> 6, lane = threadIdx.x & 63;
    if (lane == 0) { sred[wid][0] = a; sred[wid][1] = b; sred[wid][2] = c; sred[wid][3] = d; }
    __syncthreads();
    if (threadIdx.x == 0) {
        float ksum = 0, kcnt = 0, dsum = 0, scnt = 0;
#pragma unroll
        for (int w = 0; w < 4; ++w) {
            ksum += sred[w][0]; kcnt += sred[w][1]; dsum += sred[w][2]; scnt += sred[w][3];
        }
        const float known = (kcnt > 0.f) ? ksum * (1.0f / (float)NPIX) : 0.f;
        const float ddc   = (scnt > 0.f) ? dsum * (0.1f / ((float)NPIX * (float)KSEL)) : 0.f;
        out[0] = known + ddc;
        out[1] = known;
        out[2] = ddc;
    }
}

extern "C" void kernel_launch(void* const* d_in, const int* in_sizes, int n_in,
                              void* d_out, int out_size, void* d_ws, size_t ws_size,
                              hipStream_t stream) {
    const float* alpha  = (const float*)d_in[0];  // pred_alpha  [2,1,384,384]
    const float* trimap = (const float*)d_in[1];  // gt_trimap   [2,1,384,384]
    const float* image  = (const float*)d_in[2];  // input_image [2,3,384,384]
    float* out = (float*)d_out;
    float* ws  = (float*)d_ws;

    matting_main<<<NBLK, 128, 0, stream>>>(alpha, trimap, image, ws);
    matting_finalize<<<1, 256, 0, stream>>>(ws, out);
}

// Round 4
// 42.383 us; speedup vs baseline: 2.6207x; 1.0249x over previous
//
#include <hip/hip_runtime.h>
#include <math.h>

#define HH 384
#define WW 384
#define HWSZ (HH * WW)
#define NPIX (2 * HWSZ)
#define KSEL 11
#define TW 64             // tile width (one wave spans a row)
#define TH 6              // output rows per block (3 waves x 2 rows)
#define NTHR 192          // 3 waves
#define TPW (TW + 10)     // 74
#define TPH (TH + 10)     // 16
#define TILE_N (TPW * TPH)  // 1184
#define NBX (WW / TW)     // 6
#define NBY (HH / TH)     // 64
#define NBLK (2 * NBX * NBY)  // 768 = 3 * 256 -> exact CU balance

__device__ __forceinline__ float fast_sqrtf(float x) {
    float r;
    asm("v_sqrt_f32 %0, %1" : "=v"(r) : "v"(x));
    return r;
}

__device__ __forceinline__ float min3f(float a, float b, float c) {
    float r;
    asm("v_min3_f32 %0, %1, %2, %3" : "=v"(r) : "v"(a), "v"(b), "v"(c));
    return r;
}

__device__ __forceinline__ float wave_sum(float v) {
#pragma unroll
    for (int off = 32; off > 0; off >>= 1) v += __shfl_down(v, off, 64);
    return v;
}

// Key: high 20 bits = d^2 (f32 bits truncated), low 12 = pre-quantized
// neighbor alpha (staged into tile.w at load time). d2 >= 0 so float
// min/max order == lexicographic (d2, payload).
__device__ __forceinline__ float make_key(const float4 c, const float4 n) {
    const float e0 = c.x - n.x;
    const float e1 = c.y - n.y;
    const float e2 = c.z - n.z;
    float d2 = e0 * e0;
    d2 = __builtin_fmaf(e1, e1, d2);
    d2 = __builtin_fmaf(e2, e2, d2);
    const unsigned bits = (__float_as_uint(d2) & 0xFFFFF000u) | __float_as_uint(n.w);
    return __uint_as_float(bits);
}

// Merge an unsorted pair into sorted-ascending bd[0..10], keep smallest 11.
__device__ __forceinline__ void merge2(float bd[KSEL], float a, float b) {
    const float p0 = fminf(a, b);
    const float p1 = fmaxf(a, b);
    float nb[KSEL];
    nb[0] = fminf(bd[0], p0);
    nb[1] = min3f(bd[1], fmaxf(bd[0], p0), p1);
#pragma unroll
    for (int j = 2; j < KSEL; ++j)
        nb[j] = min3f(bd[j], fmaxf(bd[j - 1], p0), fmaxf(bd[j - 2], p1));
#pragma unroll
    for (int j = 0; j < KSEL; ++j) bd[j] = nb[j];
}

__device__ __forceinline__ void merge1(float bd[KSEL], float p) {
    float cd = p;
#pragma unroll
    for (int j = 0; j < KSEL; ++j) {
        const float mx = fmaxf(cd, bd[j]);
        bd[j] = fminf(cd, bd[j]);
        cd = mx;
    }
}

// Unpack selected 11 keys, accumulate |dist - (ac - alpha_n)| with exact
// center alpha ac.
__device__ __forceinline__ float acc_ddc(const float bd[KSEL], float ac) {
    float s = 0.f;
#pragma unroll
    for (int j = 0; j < KSEL; ++j) {
        const unsigned kb = __float_as_uint(bd[j]);
        const float d2 = __uint_as_float((kb & 0xFFFFF000u) | 0x800u); // midpoint
        const float ad = __builtin_fmaf((float)(kb & 0xFFFu), -1.0f / 4095.0f, ac);
        s += fabsf(fast_sqrtf(d2) - ad);
    }
    return s;
}

__global__ __launch_bounds__(NTHR) void matting_main(
    const float* __restrict__ alpha,
    const float* __restrict__ trimap,
    const float* __restrict__ image,
    float* __restrict__ ws)
{
    __shared__ float4 tile[TILE_N];   // rgb denormalized + quantized-alpha bits

    const int bx = blockIdx.x % NBX;
    const int by = (blockIdx.x / NBX) % NBY;
    const int b  = blockIdx.x / (NBX * NBY);

    const float* i0 = image + b * 3 * HWSZ;
    const float* i1 = i0 + HWSZ;
    const float* i2 = i1 + HWSZ;
    const float* ap = alpha + b * HWSZ;

    const int gy0 = by * TH - 5, gx0 = bx * TW - 5;
    for (int t = threadIdx.x; t < TILE_N; t += NTHR) {
        const int ry = t / TPW, rx = t - ry * TPW;
        const int gy = gy0 + ry, gx = gx0 + rx;
        float4 v = make_float4(0.f, 0.f, 0.f, 0.f);
        if ((unsigned)gy < (unsigned)HH && (unsigned)gx < (unsigned)WW) {
            const int gi = gy * WW + gx;
            v.x = __builtin_fmaf(i0[gi], 0.229f, 0.485f);
            v.y = __builtin_fmaf(i1[gi], 0.224f, 0.456f);
            v.z = __builtin_fmaf(i2[gi], 0.225f, 0.406f);
            v.w = __uint_as_float((unsigned)(ap[gi] * 4095.0f)); // payload bits
        }
        tile[t] = v;
    }
    __syncthreads();

    const int lane = threadIdx.x & 63;
    const int w    = threadIdx.x >> 6;            // wave id = row pair
    const float4* tp = &tile[(2 * w) * TPW + lane];
    const float4 c0 = tp[5 * TPW + 5];            // center for row y0+2w
    const float4 c1 = tp[6 * TPW + 5];            // center for row y0+2w+1

    float bd0[KSEL], bd1[KSEL];
#pragma unroll
    for (int j = 0; j < KSEL; ++j) {
        bd0[j] = __uint_as_float(0x7F800000u);
        bd1[j] = __uint_as_float(0x7F800000u);
    }

    // 12 shared window rows: row di feeds chain0 (window rows 0..10) and
    // chain1 (window rows 1..11). One ds_read serves both chains.
#pragma unroll
    for (int di = 0; di < 12; ++di) {
        const float4* row = tp + di * TPW;
#pragma unroll
        for (int h = 0; h < 5; ++h) {
            const float4 na = row[2 * h];
            const float4 nb = row[2 * h + 1];
            if (di < 11) merge2(bd0, make_key(c0, na), make_key(c0, nb));
            if (di > 0)  merge2(bd1, make_key(c1, na), make_key(c1, nb));
        }
        const float4 nz = row[10];
        if (di < 11) merge1(bd0, make_key(c0, nz));
        if (di > 0)  merge1(bd1, make_key(c1, nz));
    }

    // own-pixel terms (exact alpha / trimap from global, L2-resident)
    const int rem0 = (by * TH + 2 * w) * WW + (bx * TW + lane);
    const int rem1 = rem0 + WW;
    const float a0 = ap[rem0], a1 = ap[rem1];
    const float t0 = trimap[b * HWSZ + rem0], t1 = trimap[b * HWSZ + rem1];

    const float k0 = (t0 != 0.5f) ? 1.f : 0.f;
    const float k1 = (t1 != 0.5f) ? 1.f : 0.f;
    const float s0 = 1.f - k0, s1 = 1.f - k1;

    const float known_v = k0 * fabsf(a0 - t0) + k1 * fabsf(a1 - t1);
    const float known_c = k0 + k1;
    const float dsum = s0 * acc_ddc(bd0, a0) + s1 * acc_ddc(bd1, a1);
    const float samp = s0 + s1;

    float v0 = wave_sum(known_v);
    float v1 = wave_sum(known_c);
    float v2 = wave_sum(dsum);
    float v3 = wave_sum(samp);
    __shared__ float sred[3][4];
    if (lane == 0) { sred[w][0] = v0; sred[w][1] = v1; sred[w][2] = v2; sred[w][3] = v3; }
    __syncthreads();
    if (threadIdx.x == 0) {
        float* wsb = ws + blockIdx.x * 4;
        wsb[0] = sred[0][0] + sred[1][0] + sred[2][0];
        wsb[1] = sred[0][1] + sred[1][1] + sred[2][1];
        wsb[2] = sred[0][2] + sred[1][2] + sred[2][2];
        wsb[3] = sred[0][3] + sred[1][3] + sred[2][3];
    }
}

__global__ __launch_bounds__(256) void matting_finalize(
    const float* __restrict__ ws, float* __restrict__ out)
{
    float a = 0, b = 0, c = 0, d = 0;
    for (int i = threadIdx.x; i < NBLK; i += 256) {
        a += ws[i * 4 + 0];
        b += ws[i * 4 + 1];
        c += ws[i * 4 + 2];
        d += ws[i * 4 + 3];
    }
    a = wave_sum(a); b = wave_sum(b); c = wave_sum(c); d = wave_sum(d);
    __shared__ float sred[4][4];
    const int wid = threadIdx.x >> 6, lane = threadIdx.x & 63;
    if (lane == 0) { sred[wid][0] = a; sred[wid][1] = b; sred[wid][2] = c; sred[wid][3] = d; }
    __syncthreads();
    if (threadIdx.x == 0) {
        float ksum = 0, kcnt = 0, dsum = 0, scnt = 0;
#pragma unroll
        for (int w = 0; w < 4; ++w) {
            ksum += sred[w][0]; kcnt += sred[w][1]; dsum += sred[w][2]; scnt += sred[w][3];
        }
        const float known = (kcnt > 0.f) ? ksum * (1.0f / (float)NPIX) : 0.f;
        const float ddc   = (scnt > 0.f) ? dsum * (0.1f / ((float)NPIX * (float)KSEL)) : 0.f;
        out[0] = known + ddc;
        out[1] = known;
        out[2] = ddc;
    }
}

extern "C" void kernel_launch(void* const* d_in, const int* in_sizes, int n_in,
                              void* d_out, int out_size, void* d_ws, size_t ws_size,
                              hipStream_t stream) {
    const float* alpha  = (const float*)d_in[0];  // pred_alpha  [2,1,384,384]
    const float* trimap = (const float*)d_in[1];  // gt_trimap   [2,1,384,384]
    const float* image  = (const float*)d_in[2];  // input_image [2,3,384,384]
    float* out = (float*)d_out;
    float* ws  = (float*)d_ws;

    matting_main<<<NBLK, NTHR, 0, stream>>>(alpha, trimap, image, ws);
    matting_finalize<<<1, 256, 0, stream>>>(ws, out);
}